// Round 16
// baseline (302.285 us; speedup 1.0000x reference)
//
#include <hip/hip_runtime.h>
#include <hip/hip_fp16.h>
#include <math.h>

#define SEQ   2048
#define HID   1024
#define NH    16
#define HD    64
#define NKH   204          // heavy hitters = int(2048*0.1)
#define LCOMP 512          // compressed length = 2048/4
#define NCAT  716          // 204 + 512
#define NCATP 768          // padded to multiple of 64 (52 pad keys)
#define SCALE 0.125f       // 1/sqrt(64)

typedef __attribute__((ext_vector_type(8))) short short8;   // 8 bf16 (4 VGPRs)
typedef __attribute__((ext_vector_type(4))) float f32x4;    // MFMA accumulator

// ---- bf16 split helpers (RNE) -------------------------------------------
__device__ __forceinline__ short f2bf(float f) {
    unsigned u = __builtin_bit_cast(unsigned, f);
    u += 0x7FFFu + ((u >> 16) & 1u);
    return (short)(u >> 16);
}
__device__ __forceinline__ float bf2f(short h) {
    unsigned u = ((unsigned)(unsigned short)h) << 16;
    return __builtin_bit_cast(float, u);
}

// async global->LDS, 16B per lane (dwordx4).  LDS dest must be wave-uniform
// base; HW writes base + lane*16.  Global src is per-lane.
__device__ __forceinline__ void gload_lds16(const unsigned short* g, unsigned short* l) {
    __builtin_amdgcn_global_load_lds((const __attribute__((address_space(1))) void*)g,
                                     (__attribute__((address_space(3))) void*)l,
                                     16, 0, 0);
}

// ---------------------------------------------------------------------------
// One-pass splitters: f32 -> bf16 hi/lo.
// ---------------------------------------------------------------------------
__global__ __launch_bounds__(256) void splitx_k(const float* __restrict__ X,
                                                unsigned short* __restrict__ hi,
                                                unsigned short* __restrict__ lo) {
    size_t g = ((size_t)blockIdx.x * 256 + threadIdx.x) * 4;
    float4 v4 = *(const float4*)(X + g);
    ushort4 h4, l4;
    short hb;
    hb = f2bf(v4.x); h4.x = hb; l4.x = (unsigned short)f2bf(v4.x - bf2f(hb));
    hb = f2bf(v4.y); h4.y = hb; l4.y = (unsigned short)f2bf(v4.y - bf2f(hb));
    hb = f2bf(v4.z); h4.z = hb; l4.z = (unsigned short)f2bf(v4.z - bf2f(hb));
    hb = f2bf(v4.w); h4.w = hb; l4.w = (unsigned short)f2bf(v4.w - bf2f(hb));
    *(ushort4*)(hi + g) = h4;
    *(ushort4*)(lo + g) = l4;
}

// All 4 weight splits in one launch; blockIdx.z picks src/dst (wave-uniform).
__global__ __launch_bounds__(256) void splitw4_k(const float* __restrict__ W0,
                                                 const float* __restrict__ W1,
                                                 const float* __restrict__ W2,
                                                 const float* __restrict__ W3,
                                                 unsigned short* __restrict__ h012,
                                                 unsigned short* __restrict__ l012,
                                                 unsigned short* __restrict__ h3,
                                                 unsigned short* __restrict__ l3) {
    __shared__ float tile[64][65];
    int z = blockIdx.z;
    const float* W = (z == 0) ? W0 : (z == 1) ? W1 : (z == 2) ? W2 : W3;
    unsigned short* hi = (z == 3) ? h3 : h012 + (size_t)z * HID * HID;
    unsigned short* lo = (z == 3) ? l3 : l012 + (size_t)z * HID * HID;
    int n0 = blockIdx.x * 64, k0 = blockIdx.y * 64;
    int t = threadIdx.x;
    int r = t >> 4, c4 = (t & 15) * 4;
    #pragma unroll
    for (int i = 0; i < 4; ++i) {
        float4 v4 = *(const float4*)(W + (size_t)(k0 + i*16 + r) * HID + n0 + c4);
        tile[i*16 + r][c4+0] = v4.x; tile[i*16 + r][c4+1] = v4.y;
        tile[i*16 + r][c4+2] = v4.z; tile[i*16 + r][c4+3] = v4.w;
    }
    __syncthreads();
    #pragma unroll
    for (int i = 0; i < 4; ++i) {
        int n = i*16 + r;
        float v0 = tile[c4+0][n], v1 = tile[c4+1][n];
        float v2 = tile[c4+2][n], v3 = tile[c4+3][n];
        ushort4 h4, l4;
        short hb;
        hb = f2bf(v0); h4.x = hb; l4.x = (unsigned short)f2bf(v0 - bf2f(hb));
        hb = f2bf(v1); h4.y = hb; l4.y = (unsigned short)f2bf(v1 - bf2f(hb));
        hb = f2bf(v2); h4.z = hb; l4.z = (unsigned short)f2bf(v2 - bf2f(hb));
        hb = f2bf(v3); h4.w = hb; l4.w = (unsigned short)f2bf(v3 - bf2f(hb));
        size_t o = (size_t)(n0 + n) * HID + k0 + c4;
        *(ushort4*)(hi + o) = h4;
        *(ushort4*)(lo + o) = l4;
    }
}

// ---------------------------------------------------------------------------
// LDS-staged bf16x3 MFMA GEMM.  Block = BM x BN, BK=64 (r16), 4 waves,
// wave = (BM/2)m x (BN/2)n.  MODE 1 = fused QKV epilogue, MODE 0 = f32 C.
// r16: BK 32 -> 64 with the score-kernel XOR chunk swizzle (proven r10+,
// zero bank conflicts there): halves barrier-pairs per block (32 -> 16)
// and makes fragment ds_read_b128 conflict-free (old [row][32] layout was
// 8-way conflicted, 4.7M cycles).  k-slice order unchanged (kt asc, ks asc
// == old kt+32*ks) -> bitwise-identical accumulation.  LDS 48 KB (BM=128):
// still 3 blocks/CU.
// ---------------------------------------------------------------------------
template<int BM, int BN, int MODE>
__global__ __launch_bounds__(256) void gemm_lds(const unsigned short* __restrict__ Ahi,
                                                const unsigned short* __restrict__ Alo,
                                                const unsigned short* __restrict__ Bthi,
                                                const unsigned short* __restrict__ Btlo,
                                                unsigned short* __restrict__ qhi,
                                                unsigned short* __restrict__ qlo,
                                                float* __restrict__ kf,
                                                unsigned short* __restrict__ khi,
                                                unsigned short* __restrict__ klo,
                                                float* __restrict__ vf,
                                                float* __restrict__ Cf) {
    constexpr int WM = BM / 2, WN = BN / 2;
    constexpr int MT = WM / 16, NT = WN / 16;
    __shared__ __align__(16) unsigned short Ah_s[BM * 64];
    __shared__ __align__(16) unsigned short Al_s[BM * 64];
    __shared__ __align__(16) unsigned short Bh_s[BN * 64];
    __shared__ __align__(16) unsigned short Bl_s[BN * 64];
    int t = threadIdx.x, lane = t & 63, w = t >> 6;
    int quad = lane >> 4, c16 = lane & 15;
    int m0 = blockIdx.x * BM, n0 = blockIdx.y * BN;
    int moff = (w & 1) * WM, noff = (w >> 1) * WN;

    f32x4 acc[MT][NT];
    #pragma unroll
    for (int mt = 0; mt < MT; ++mt)
        #pragma unroll
        for (int nt = 0; nt < NT; ++nt)
            acc[mt][nt] = (f32x4){0.f, 0.f, 0.f, 0.f};

    for (int kt = 0; kt < HID; kt += 64) {
        __syncthreads();
        // stage A [BM][64] and B [BN][64] hi/lo, 16B chunks, XOR-swizzled
        // via the global source (LDS dest linear; read un-swizzles).
        #pragma unroll
        for (int j = 0; j < BM / 32; ++j) {
            int nb = j * 256 + w * 64;       // wave-uniform LDS chunk base
            int n  = nb + lane;
            int row = n >> 3;                // tile row
            int sc  = ((n & 7) ^ (row & 7)) * 8;   // swizzled source chunk
            gload_lds16(Ahi + (size_t)(m0 + row) * HID + kt + sc, Ah_s + nb*8);
            gload_lds16(Alo + (size_t)(m0 + row) * HID + kt + sc, Al_s + nb*8);
        }
        #pragma unroll
        for (int j = 0; j < BN / 32; ++j) {
            int nb = j * 256 + w * 64;
            int n  = nb + lane;
            int row = n >> 3;
            int sc  = ((n & 7) ^ (row & 7)) * 8;
            gload_lds16(Bthi + (size_t)(n0 + row) * HID + kt + sc, Bh_s + nb*8);
            gload_lds16(Btlo + (size_t)(n0 + row) * HID + kt + sc, Bl_s + nb*8);
        }
        __syncthreads();
        #pragma unroll
        for (int ks = 0; ks < 2; ++ks) {     // two 32-k slices, ascending k
            short8 Bh[NT], Bl[NT];
            #pragma unroll
            for (int nt = 0; nt < NT; ++nt) {
                int row = noff + nt * 16 + c16;
                int s = ((ks*4 + quad) ^ (row & 7)) * 8;
                Bh[nt] = *(const short8*)&Bh_s[row * 64 + s];
                Bl[nt] = *(const short8*)&Bl_s[row * 64 + s];
            }
            #pragma unroll
            for (int mt = 0; mt < MT; ++mt) {
                int row = moff + mt * 16 + c16;
                int s = ((ks*4 + quad) ^ (row & 7)) * 8;
                short8 Ah = *(const short8*)&Ah_s[row * 64 + s];
                short8 Al = *(const short8*)&Al_s[row * 64 + s];
                #pragma unroll
                for (int nt = 0; nt < NT; ++nt) {
                    acc[mt][nt] = __builtin_amdgcn_mfma_f32_16x16x32_bf16(Ah, Bh[nt], acc[mt][nt], 0, 0, 0);
                    acc[mt][nt] = __builtin_amdgcn_mfma_f32_16x16x32_bf16(Al, Bh[nt], acc[mt][nt], 0, 0, 0);
                    acc[mt][nt] = __builtin_amdgcn_mfma_f32_16x16x32_bf16(Ah, Bl[nt], acc[mt][nt], 0, 0, 0);
                }
            }
        }
    }

    #pragma unroll
    for (int mt = 0; mt < MT; ++mt)
    #pragma unroll
    for (int nt = 0; nt < NT; ++nt)
    #pragma unroll
    for (int i = 0; i < 4; ++i) {
        int m  = m0 + moff + mt * 16 + quad * 4 + i;
        int ng = n0 + noff + nt * 16 + c16;
        float val = acc[mt][nt][i];
        if (MODE == 1) {
            int seg = ng >> 10;            // 0=q, 1=k, 2=v
            int nl  = ng & 1023;
            if (seg == 0) {
                size_t o = ((size_t)(nl >> 6) * SEQ + m) * HD + (nl & 63);
                short hb = f2bf(val);
                qhi[o] = (unsigned short)hb;
                qlo[o] = (unsigned short)f2bf(val - bf2f(hb));
            } else if (seg == 1) {
                kf[(size_t)m * HID + nl] = val;
                size_t o = ((size_t)(nl >> 6) * SEQ + m) * HD + (nl & 63);
                short hb = f2bf(val);
                khi[o] = (unsigned short)hb;
                klo[o] = (unsigned short)f2bf(val - bf2f(hb));
            } else {
                vf[(size_t)m * HID + nl] = val;
            }
        } else {
            Cf[(size_t)m * HID + ng] = val;
        }
    }
}

// ---------------------------------------------------------------------------
// Score pipeline: key-split 3-dispatch (r10/r11, kept).
// ---------------------------------------------------------------------------
__global__ __launch_bounds__(256) void score1_k(const unsigned short* __restrict__ qhi,
                                                const unsigned short* __restrict__ qlo,
                                                const unsigned short* __restrict__ khi,
                                                const unsigned short* __restrict__ klo,
                                                float* __restrict__ lp,
                                                float* __restrict__ eep,
                                                float* __restrict__ mxp) {
    __shared__ __align__(16) unsigned short Kh_s[128 * 64];  // 16 KB
    __shared__ __align__(16) unsigned short Kl_s[128 * 64];  // 16 KB
    int lin = blockIdx.x;
    int swz = (lin & 7) * 128 + (lin >> 3);  // bijective XCD swizzle (1024%8==0)
    int h   = swz >> 6;
    int rem = swz & 63;
    int qb  = rem >> 1;
    int kh2 = rem & 1;                       // key half
    int m0 = qb * 64;
    int kbase = kh2 * 1024;
    int t  = threadIdx.x;
    int lane = t & 63, w = t >> 6;           // w = wave = 16-row group
    int quad = lane >> 4, c16 = lane & 15;

    const unsigned short* qph = qhi + ((size_t)h * SEQ + m0 + w*16 + c16) * HD;
    const unsigned short* qpl = qlo + ((size_t)h * SEQ + m0 + w*16 + c16) * HD;
    short8 Ah0 = *(const short8*)(qph + quad*8);
    short8 Ah1 = *(const short8*)(qph + 32 + quad*8);
    short8 Al0 = *(const short8*)(qpl + quad*8);
    short8 Al1 = *(const short8*)(qpl + 32 + quad*8);

    float l[4] = {}, ee[4] = {};
    float mx[4] = {-1e30f, -1e30f, -1e30f, -1e30f};

    for (int kt = 0; kt < 8; ++kt) {
        int key0 = kbase + kt * 128;
        __syncthreads();
        #pragma unroll
        for (int j = 0; j < 4; ++j) {
            int nb = j*256 + w*64;           // wave-uniform LDS chunk base
            int n  = nb + lane;
            int row = n >> 3;                // key within tile
            int sc  = ((n & 7) ^ (row & 7)) * 8;   // swizzled source chunk
            gload_lds16(khi + ((size_t)h * SEQ + key0 + row) * HD + sc, Kh_s + nb*8);
            gload_lds16(klo + ((size_t)h * SEQ + key0 + row) * HD + sc, Kl_s + nb*8);
        }
        __syncthreads();
        #pragma unroll
        for (int ksub = 0; ksub < 8; ++ksub) {
            int q  = ksub*16 + c16;
            int s0 = (quad       ^ (q & 7)) * 8;
            int s1 = ((quad + 4) ^ (q & 7)) * 8;
            short8 Bh0 = *(const short8*)&Kh_s[q*64 + s0];
            short8 Bh1 = *(const short8*)&Kh_s[q*64 + s1];
            short8 Bl0 = *(const short8*)&Kl_s[q*64 + s0];
            short8 Bl1 = *(const short8*)&Kl_s[q*64 + s1];
            f32x4 acc = {0.f, 0.f, 0.f, 0.f};
            acc = __builtin_amdgcn_mfma_f32_16x16x32_bf16(Ah0, Bh0, acc, 0, 0, 0);
            acc = __builtin_amdgcn_mfma_f32_16x16x32_bf16(Al0, Bh0, acc, 0, 0, 0);
            acc = __builtin_amdgcn_mfma_f32_16x16x32_bf16(Ah0, Bl0, acc, 0, 0, 0);
            acc = __builtin_amdgcn_mfma_f32_16x16x32_bf16(Ah1, Bh1, acc, 0, 0, 0);
            acc = __builtin_amdgcn_mfma_f32_16x16x32_bf16(Al1, Bh1, acc, 0, 0, 0);
            acc = __builtin_amdgcn_mfma_f32_16x16x32_bf16(Ah1, Bl1, acc, 0, 0, 0);
            #pragma unroll
            for (int i = 0; i < 4; ++i) {
                float s = acc[i] * SCALE;
                float e = __expf(s);          // safe: |s| << 88
                l[i]  += e;
                ee[i] += e * s;
                mx[i]  = fmaxf(mx[i], s);
            }
        }
    }

    #pragma unroll
    for (int i = 0; i < 4; ++i) {
        #pragma unroll
        for (int off = 1; off <= 8; off <<= 1) {
            l[i]  += __shfl_xor(l[i], off);
            ee[i] += __shfl_xor(ee[i], off);
            mx[i]  = fmaxf(mx[i], __shfl_xor(mx[i], off));
        }
    }
    if (c16 == 0) {
        #pragma unroll
        for (int i = 0; i < 4; ++i) {
            size_t o = ((size_t)kh2 * NH + h) * SEQ + m0 + w*16 + quad*4 + i;
            lp[o]  = l[i];
            eep[o] = ee[i];
            mxp[o] = mx[i];
        }
    }
}

// combine key-half partials -> inv, ent, mxa
__global__ __launch_bounds__(256) void fixstats_k(const float* __restrict__ lp,
                                                  const float* __restrict__ eep,
                                                  const float* __restrict__ mxp,
                                                  float* __restrict__ invg,
                                                  float* __restrict__ ent,
                                                  float* __restrict__ mxa) {
    int idx = blockIdx.x * 256 + threadIdx.x;    // h*SEQ + row
    float lf  = lp[idx]  + lp[(size_t)NH*SEQ + idx];
    float eef = eep[idx] + eep[(size_t)NH*SEQ + idx];
    float mf  = fmaxf(mxp[idx], mxp[(size_t)NH*SEQ + idx]);
    float iv = 1.f / lf;
    invg[idx] = iv;
    mxa[idx] = __expf(mf) * iv;
    ent[idx] = __logf(lf) - eef * iv;
}

__global__ __launch_bounds__(256) void score2_k(const unsigned short* __restrict__ qhi,
                                                const unsigned short* __restrict__ qlo,
                                                const unsigned short* __restrict__ khi,
                                                const unsigned short* __restrict__ klo,
                                                const float* __restrict__ invg,
                                                __half* __restrict__ part) {
    __shared__ __align__(16) unsigned short Kh_s[128 * 64];  // 16 KB
    __shared__ __align__(16) unsigned short Kl_s[128 * 64];  // 16 KB
    int lin = blockIdx.x;
    int swz = (lin & 7) * 128 + (lin >> 3);  // bijective XCD swizzle
    int h   = swz >> 6;
    int rem = swz & 63;
    int qb  = rem >> 1;
    int kh2 = rem & 1;
    int m0 = qb * 64;
    int kbase = kh2 * 1024;
    int t  = threadIdx.x;
    int lane = t & 63, w = t >> 6;
    int quad = lane >> 4, c16 = lane & 15;

    const unsigned short* qph = qhi + ((size_t)h * SEQ + m0 + w*16 + c16) * HD;
    const unsigned short* qpl = qlo + ((size_t)h * SEQ + m0 + w*16 + c16) * HD;
    short8 Ah0 = *(const short8*)(qph + quad*8);
    short8 Ah1 = *(const short8*)(qph + 32 + quad*8);
    short8 Al0 = *(const short8*)(qpl + quad*8);
    short8 Al1 = *(const short8*)(qpl + 32 + quad*8);

    float invv[4];
    #pragma unroll
    for (int i = 0; i < 4; ++i)
        invv[i] = invg[(size_t)h * SEQ + m0 + w*16 + quad*4 + i];

    __half* pslab = part + ((size_t)(h * 32 + qb) * 4 + w) * SEQ;
    for (int kt = 0; kt < 8; ++kt) {
        int key0 = kbase + kt * 128;
        __syncthreads();
        #pragma unroll
        for (int j = 0; j < 4; ++j) {
            int nb = j*256 + w*64;
            int n  = nb + lane;
            int row = n >> 3;
            int sc  = ((n & 7) ^ (row & 7)) * 8;
            gload_lds16(khi + ((size_t)h * SEQ + key0 + row) * HD + sc, Kh_s + nb*8);
            gload_lds16(klo + ((size_t)h * SEQ + key0 + row) * HD + sc, Kl_s + nb*8);
        }
        __syncthreads();
        #pragma unroll
        for (int ksub = 0; ksub < 8; ++ksub) {
            int q  = ksub*16 + c16;
            int s0 = (quad       ^ (q & 7)) * 8;
            int s1 = ((quad + 4) ^ (q & 7)) * 8;
            short8 Bh0 = *(const short8*)&Kh_s[q*64 + s0];
            short8 Bh1 = *(const short8*)&Kh_s[q*64 + s1];
            short8 Bl0 = *(const short8*)&Kl_s[q*64 + s0];
            short8 Bl1 = *(const short8*)&Kl_s[q*64 + s1];
            f32x4 acc = {0.f, 0.f, 0.f, 0.f};
            acc = __builtin_amdgcn_mfma_f32_16x16x32_bf16(Ah0, Bh0, acc, 0, 0, 0);
            acc = __builtin_amdgcn_mfma_f32_16x16x32_bf16(Al0, Bh0, acc, 0, 0, 0);
            acc = __builtin_amdgcn_mfma_f32_16x16x32_bf16(Ah0, Bl0, acc, 0, 0, 0);
            acc = __builtin_amdgcn_mfma_f32_16x16x32_bf16(Ah1, Bh1, acc, 0, 0, 0);
            acc = __builtin_amdgcn_mfma_f32_16x16x32_bf16(Al1, Bh1, acc, 0, 0, 0);
            acc = __builtin_amdgcn_mfma_f32_16x16x32_bf16(Ah1, Bl1, acc, 0, 0, 0);
            float cs = 0.f;
            #pragma unroll
            for (int i = 0; i < 4; ++i)
                cs += __expf(acc[i] * SCALE) * invv[i];
            cs += __shfl_xor(cs, 16);
            cs += __shfl_xor(cs, 32);    // sum over the 4 quads (16 rows)
            if (quad == 0)
                pslab[key0 + ksub*16 + c16] = __float2half(cs);
        }
    }
}

// stage-1 influence reduction: red[h][s] = sum of head h's 128 wave-slabs
__global__ __launch_bounds__(256) void reduce_infl(const __half* __restrict__ part,
                                                   float* __restrict__ red) {
    int s = blockIdx.x * 256 + threadIdx.x;
    int g = blockIdx.y;
    const __half* p = part + (size_t)g * 128 * SEQ + s;
    float a = 0.f;
    #pragma unroll 16
    for (int i = 0; i < 128; ++i) a += __half2float(p[(size_t)i * SEQ]);
    red[(size_t)g * SEQ + s] = a;
}

__global__ __launch_bounds__(256) void importance_k(const float* __restrict__ ent,
                                                    const float* __restrict__ mxa,
                                                    const float* __restrict__ red,
                                                    float* __restrict__ imp) {
    int s = blockIdx.x * 256 + threadIdx.x;
    float es = 0.f, ms = 0.f;
    #pragma unroll
    for (int h = 0; h < NH; ++h) { es += ent[h*SEQ + s]; ms += mxa[h*SEQ + s]; }
    float inf = 0.f;
    #pragma unroll
    for (int g = 0; g < NH; ++g) inf += red[(size_t)g * SEQ + s];
    imp[s] = (-0.4f*es + 0.3f*ms + 0.3f*inf) * (1.f/16.f);
}

// Deterministic top-k by rank counting — wave-parallel (r13, kept: 76 -> ~3 us).
__global__ __launch_bounds__(256) void topk_k(const float* __restrict__ imp,
                                              int* __restrict__ hh) {
    __shared__ float si[SEQ];
    int t = threadIdx.x;
    for (int i = t; i < SEQ; i += 256) si[i] = imp[i];
    __syncthreads();
    int lane = t & 63, w = t >> 6;
    int s = blockIdx.x * 4 + w;
    float v = si[s];
    int rank = 0;
    #pragma unroll
    for (int j = 0; j < SEQ / 64; ++j) {
        int i = j * 64 + lane;
        float u = si[i];
        rank += (u > v) || (u == v && i < s);
    }
    #pragma unroll
    for (int off = 32; off; off >>= 1) rank += __shfl_xor(rank, off);
    if (lane == 0 && rank < NKH) hh[rank] = s;
}

// per-(h,s) L2 norms for BOTH k and v (blockIdx.y selects tensor)
__global__ __launch_bounds__(256) void norms2_k(const float* __restrict__ kf,
                                                const float* __restrict__ vf,
                                                float* __restrict__ wk,
                                                float* __restrict__ wv) {
    int sel = blockIdx.y;
    const float* x = sel ? vf : kf;
    float* n = sel ? wv : wk;
    int t = threadIdx.x;
    int wid = blockIdx.x * 4 + (t >> 6);
    int lane = t & 63;
    int h = wid >> 11, s = wid & 2047;
    float v = x[(size_t)s * HID + h * HD + lane];
    float ss = v * v;
    #pragma unroll
    for (int off = 32; off; off >>= 1) ss += __shfl_xor(ss, off);
    if (lane == 0) n[h*SEQ + s] = sqrtf(ss);
}

// in-place softmax over SEQ per head for BOTH wk and wv
__global__ __launch_bounds__(256) void softw2_k(float* __restrict__ wk,
                                                float* __restrict__ wv) {
    __shared__ float red[8];
    int h = blockIdx.x, t = threadIdx.x, lane = t & 63, w = t >> 6;
    float* nh = (blockIdx.y ? wv : wk) + (size_t)h * SEQ;
    float m = -1e30f;
    for (int i = t; i < SEQ; i += 256) m = fmaxf(m, nh[i]);
    #pragma unroll
    for (int off = 32; off; off >>= 1) m = fmaxf(m, __shfl_xor(m, off));
    if (lane == 0) red[w] = m;
    __syncthreads();
    m = fmaxf(fmaxf(red[0], red[1]), fmaxf(red[2], red[3]));
    float z = 0.f;
    for (int i = t; i < SEQ; i += 256) z += __expf(nh[i] - m);
    #pragma unroll
    for (int off = 32; off; off >>= 1) z += __shfl_xor(z, off);
    if (lane == 0) red[4 + w] = z;
    __syncthreads();
    z = red[4] + red[5] + red[6] + red[7];
    for (int i = t; i < SEQ; i += 256) nh[i] = __expf(nh[i] - m) / z;
}

// group-4 weighted pooling of K (direct) and V (transposed) in one launch
__global__ __launch_bounds__(256) void pool2_k(const float* __restrict__ kf,
                                               const float* __restrict__ vf,
                                               const float* __restrict__ wk,
                                               const float* __restrict__ wv,
                                               unsigned short* __restrict__ khi,
                                               unsigned short* __restrict__ klo,
                                               unsigned short* __restrict__ vthi,
                                               unsigned short* __restrict__ vtlo) {
    int sel = blockIdx.y;
    const float* src = sel ? vf : kf;
    const float* w   = sel ? wv : wk;
    int g = blockIdx.x * 256 + threadIdx.x;
    int d = g & 63, rest = g >> 6;
    int l = rest & 511, h = rest >> 9;
    const float* wp = w + (size_t)h * SEQ + l * 4;
    float w0 = wp[0], w1 = wp[1], w2 = wp[2], w3 = wp[3];
    float wsum = w0 + w1 + w2 + w3 + 1e-8f;
    size_t base = (size_t)(l*4) * HID + h * HD + d;
    float val = (src[base]*w0 + src[base+HID]*w1 + src[base+2*HID]*w2 + src[base+3*HID]*w3) / wsum;
    short hb = f2bf(val);
    if (sel) {
        size_t dst = ((size_t)h * HD + d) * NCATP + NKH + l;
        vthi[dst] = (unsigned short)hb;
        vtlo[dst] = (unsigned short)f2bf(val - bf2f(hb));
    } else {
        size_t dst = ((size_t)h * NCATP + NKH + l) * HD + d;
        khi[dst] = (unsigned short)hb;
        klo[dst] = (unsigned short)f2bf(val - bf2f(hb));
    }
}

// gather heavy-hitter k/v rows -> pre-split bf16 (K direct, V transposed)
__global__ __launch_bounds__(256) void gather_k(const float* __restrict__ k,
                                                const float* __restrict__ v,
                                                const int* __restrict__ hh,
                                                unsigned short* __restrict__ khi,
                                                unsigned short* __restrict__ klo,
                                                unsigned short* __restrict__ vthi,
                                                unsigned short* __restrict__ vtlo) {
    int g = blockIdx.x * 256 + threadIdx.x;
    int d = g & 63, rest = g >> 6;
    int i = rest % NKH, h = rest / NKH;
    int s = hh[i];
    float kv = k[(size_t)s * HID + h * HD + d];
    float vv = v[(size_t)s * HID + h * HD + d];
    size_t kd = ((size_t)h * NCATP + i) * HD + d;
    size_t vd = ((size_t)h * HD + d) * NCATP + i;
    short hb = f2bf(kv);
    khi[kd] = (unsigned short)hb;
    klo[kd] = (unsigned short)f2bf(kv - bf2f(hb));
    hb = f2bf(vv);
    vthi[vd] = (unsigned short)hb;
    vtlo[vd] = (unsigned short)f2bf(vv - bf2f(hb));
}

// zero the 52 pad keys per head in all four split arrays
__global__ __launch_bounds__(256) void padzero_k(unsigned short* __restrict__ khi,
                                                 unsigned short* __restrict__ klo,
                                                 unsigned short* __restrict__ vthi,
                                                 unsigned short* __restrict__ vtlo) {
    int g = blockIdx.x * 256 + threadIdx.x;
    if (g >= NH * (NCATP - NCAT) * HD) return;
    int d = g & 63, rest = g >> 6;
    int i = rest % (NCATP - NCAT), h = rest / (NCATP - NCAT);
    size_t kd = ((size_t)h * NCATP + NCAT + i) * HD + d;
    size_t vd = ((size_t)h * HD + d) * NCATP + NCAT + i;
    khi[kd] = 0; klo[kd] = 0;
    vthi[vd] = 0; vtlo[vd] = 0;
}

// ---------------------------------------------------------------------------
// Final attention — LDS-staged flash-style (r6, kept: 101.6 -> ~30 us).
// ---------------------------------------------------------------------------
__global__ __launch_bounds__(256) void attn_mfma(const unsigned short* __restrict__ qhi,
                                                 const unsigned short* __restrict__ qlo,
                                                 const unsigned short* __restrict__ kchi,
                                                 const unsigned short* __restrict__ kclo,
                                                 const unsigned short* __restrict__ vthi,
                                                 const unsigned short* __restrict__ vtlo,
                                                 unsigned short* __restrict__ aohi,
                                                 unsigned short* __restrict__ aolo) {
    __shared__ __align__(16) unsigned short Kh_s[64 * 64];   // [key][d-chunk swz]
    __shared__ __align__(16) unsigned short Kl_s[64 * 64];
    __shared__ __align__(16) unsigned short Vh_s[64 * 64];   // [dim][k-chunk swz]
    __shared__ __align__(16) unsigned short Vl_s[64 * 64];
    __shared__ __align__(16) unsigned short Ph_s[4][16][72]; // [wave][row][key]
    __shared__ __align__(16) unsigned short Pl_s[4][16][72];

    int lin = blockIdx.x;
    int swz = (lin & 7) * 64 + (lin >> 3);   // bijective XCD swizzle (512%8==0)
    int h  = swz >> 5;
    int m0 = (swz & 31) * 64;
    int t  = threadIdx.x;
    int lane = t & 63, w = t >> 6;           // w = wave = 16-row group
    int quad = lane >> 4, c16 = lane & 15;

    // Q fragments for this wave's 16 rows
    const unsigned short* qph = qhi + ((size_t)h * SEQ + m0 + w*16 + c16) * HD;
    const unsigned short* qpl = qlo + ((size_t)h * SEQ + m0 + w*16 + c16) * HD;
    short8 Ah0 = *(const short8*)(qph + quad*8);
    short8 Ah1 = *(const short8*)(qph + 32 + quad*8);
    short8 Al0 = *(const short8*)(qpl + quad*8);
    short8 Al1 = *(const short8*)(qpl + 32 + quad*8);

    f32x4 ohh[4], olh[4], ohl[4];
    #pragma unroll
    for (int dt = 0; dt < 4; ++dt) {
        ohh[dt] = (f32x4){0.f,0.f,0.f,0.f};
        olh[dt] = (f32x4){0.f,0.f,0.f,0.f};
        ohl[dt] = (f32x4){0.f,0.f,0.f,0.f};
    }
    float l[4] = {};

    for (int kt = 0; kt < 12; ++kt) {
        int key0 = kt * 64;
        __syncthreads();                 // prev tile's LDS readers done
        #pragma unroll
        for (int j = 0; j < 2; ++j) {
            int nb = j*256 + (t & 192);  // wave-uniform LDS chunk base
            int n  = nb + lane;
            int row = n >> 3;            // key (K) / dim (V)
            int sc  = ((n & 7) ^ (row & 7)) * 8;   // swizzled source chunk (shorts)
            gload_lds16(kchi + ((size_t)h * NCATP + key0 + row) * HD + sc, Kh_s + nb*8);
            gload_lds16(kclo + ((size_t)h * NCATP + key0 + row) * HD + sc, Kl_s + nb*8);
            gload_lds16(vthi + ((size_t)h * HD + row) * NCATP + key0 + sc, Vh_s + nb*8);
            gload_lds16(vtlo + ((size_t)h * HD + row) * NCATP + key0 + sc, Vl_s + nb*8);
        }
        __syncthreads();                 // drain: tiles ready

        // ---- QK: 4 sub-tiles of 16 keys ----
        #pragma unroll
        for (int ksub = 0; ksub < 4; ++ksub) {
            int q  = ksub*16 + c16;      // key row in LDS (lane's B column)
            int s0 = (quad       ^ (q & 7)) * 8;
            int s1 = ((quad + 4) ^ (q & 7)) * 8;
            short8 Bh0 = *(const short8*)&Kh_s[q*64 + s0];
            short8 Bh1 = *(const short8*)&Kh_s[q*64 + s1];
            short8 Bl0 = *(const short8*)&Kl_s[q*64 + s0];
            short8 Bl1 = *(const short8*)&Kl_s[q*64 + s1];
            f32x4 acc = {0.f, 0.f, 0.f, 0.f};
            acc = __builtin_amdgcn_mfma_f32_16x16x32_bf16(Ah0, Bh0, acc, 0, 0, 0);
            acc = __builtin_amdgcn_mfma_f32_16x16x32_bf16(Al0, Bh0, acc, 0, 0, 0);
            acc = __builtin_amdgcn_mfma_f32_16x16x32_bf16(Ah0, Bl0, acc, 0, 0, 0);
            acc = __builtin_amdgcn_mfma_f32_16x16x32_bf16(Ah1, Bh1, acc, 0, 0, 0);
            acc = __builtin_amdgcn_mfma_f32_16x16x32_bf16(Al1, Bh1, acc, 0, 0, 0);
            acc = __builtin_amdgcn_mfma_f32_16x16x32_bf16(Ah1, Bl1, acc, 0, 0, 0);
            bool ok = (key0 + q) < NCAT;
            #pragma unroll
            for (int i = 0; i < 4; ++i) {
                float e = ok ? __expf(acc[i] * SCALE) : 0.f;
                l[i] += e;
                short eh = f2bf(e);
                Ph_s[w][quad*4 + i][ksub*16 + c16] = (unsigned short)eh;
                Pl_s[w][quad*4 + i][ksub*16 + c16] = (unsigned short)f2bf(e - bf2f(eh));
            }
        }

        // ---- PV: 4 dim-tiles x 2 k-steps (same-wave P dep; compiler waits) ----
        #pragma unroll
        for (int dt = 0; dt < 4; ++dt) {
            int dl = dt*16 + c16;        // dim row in LDS (lane's B column)
            #pragma unroll
            for (int ks = 0; ks < 2; ++ks) {
                short8 Ph = *(const short8*)&Ph_s[w][c16][ks*32 + quad*8];
                short8 Pl = *(const short8*)&Pl_s[w][c16][ks*32 + quad*8];
                int sv = ((ks*4 + quad) ^ (dl & 7)) * 8;
                short8 Vh = *(const short8*)&Vh_s[dl*64 + sv];
                short8 Vl = *(const short8*)&Vl_s[dl*64 + sv];
                ohh[dt] = __builtin_amdgcn_mfma_f32_16x16x32_bf16(Ph, Vh, ohh[dt], 0, 0, 0);
                olh[dt] = __builtin_amdgcn_mfma_f32_16x16x32_bf16(Pl, Vh, olh[dt], 0, 0, 0);
                ohl[dt] = __builtin_amdgcn_mfma_f32_16x16x32_bf16(Ph, Vl, ohl[dt], 0, 0, 0);
            }
        }
    }

    // ---- epilogue: l reduce over the 16-lane key group, normalize, write ----
    #pragma unroll
    for (int i = 0; i < 4; ++i) {
        #pragma unroll
        for (int off = 1; off <= 8; off <<= 1) l[i] += __shfl_xor(l[i], off);
    }
    float inv[4];
    #pragma unroll
    for (int i = 0; i < 4; ++i) inv[i] = 1.f / l[i];

    #pragma unroll
    for (int dt = 0; dt < 4; ++dt)
    #pragma unroll
    for (int i = 0; i < 4; ++i) {
        float val = (ohh[dt][i] + olh[dt][i] + ohl[dt][i]) * inv[i];
        int row = m0 + w*16 + quad*4 + i;
        int dim = dt*16 + c16;
        size_t o = (size_t)row * HID + h * HD + dim;
        short hb = f2bf(val);
        aohi[o] = (unsigned short)hb;
        aolo[o] = (unsigned short)f2bf(val - bf2f(hb));
    }
}

// ---------------------------------------------------------------------------
extern "C" void kernel_launch(void* const* d_in, const int* in_sizes, int n_in,
                              void* d_out, int out_size, void* d_ws, size_t ws_size,
                              hipStream_t stream) {
    const float* x  = (const float*)d_in[0];
    const float* Wq = (const float*)d_in[1];
    const float* Wk = (const float*)d_in[2];
    const float* Wv = (const float*)d_in[3];
    const float* Wo = (const float*)d_in[4];
    float* out = (float*)d_out;

    char* base = (char*)d_ws;                       // 58 MB total
    const size_t MB = 1u << 20;
    float* kf = (float*)(base + 0);                 // 8 MB
    float* vf = (float*)(base + 8*MB);              // 8 MB
    unsigned short* xhi = (unsigned short*)(base + 16*MB);   // 4 MB
    unsigned short* xlo = (unsigned short*)(base + 20*MB);   // 4 MB
    unsigned short* wallhi = (unsigned short*)(base + 24*MB); // 6 MB [Wq|Wk|Wv]
    unsigned short* walllo = (unsigned short*)(base + 30*MB); // 6 MB
    unsigned short* wohi = (unsigned short*)(base + 36*MB);  // 2 MB
    unsigned short* wolo = (unsigned short*)(base + 38*MB);  // 2 MB
    unsigned short* qsphi = (unsigned short*)(base + 40*MB); // 4 MB [h][s][d]
    unsigned short* qsplo = (unsigned short*)(base + 44*MB);
    unsigned short* ksphi = (unsigned short*)(base + 48*MB); // 4 MB [h][s][d]
    unsigned short* ksplo = (unsigned short*)(base + 52*MB);
    // aliases (ordered reuse on the in-order stream):
    unsigned short* aohi = xhi;                     // x dead after gemm_qkv
    unsigned short* aolo = xlo;
    __half* part = (__half*)(base + 16*MB);         // 8 MB (xhi+xlo region):
                                                    // written after gemm_qkv,
                                                    // consumed by reduce_infl
                                                    // before attn_mfma writes ao
    const size_t CATB = (size_t)NH * NCATP * HD * 2; // 1.5 MB
    unsigned short* kchi = (unsigned short*)(base + 48*MB);  // after score path
    unsigned short* kclo = (unsigned short*)(base + 48*MB + CATB);
    unsigned short* vthi = (unsigned short*)(base + 48*MB + 2*CATB);
    unsigned short* vtlo = (unsigned short*)(base + 48*MB + 3*CATB);
    // small buffers
    char* sm = base + 56*MB;
    float* ent  = (float*)sm;                 sm += NH*SEQ*4;
    float* mxa  = (float*)sm;                 sm += NH*SEQ*4;
    float* imp  = (float*)sm;                 sm += SEQ*4;
    int*   hh   = (int*)sm;                   sm += 256*4;
    float* wk   = (float*)sm;                 sm += NH*SEQ*4;
    float* wv   = (float*)sm;                 sm += NH*SEQ*4;
    float* red  = (float*)sm;                 sm += NH*SEQ*4;   // 128 KB
    float* lp   = (float*)sm;                 sm += 2*NH*SEQ*4; // 256 KB
    float* eep  = (float*)sm;                 sm += 2*NH*SEQ*4; // 256 KB
    float* mxp  = (float*)sm;                 sm += 2*NH*SEQ*4; // 256 KB
    float* invg = (float*)sm;                 // 128 KB  (total ~1.54 MB < 2 MB)

    // 1. split inputs (one launch for all 4 weights)
    splitx_k<<<SEQ*HID/1024, 256, 0, stream>>>(x, xhi, xlo);
    splitw4_k<<<dim3(16,16,4), 256, 0, stream>>>(Wq, Wk, Wv, Wo,
                                                 wallhi, walllo, wohi, wolo);

    // 2. fused QKV projection (128x64 tile, BK=64 swizzled staging:
    //    halved barriers, conflict-free fragment reads)
    gemm_lds<128, 64, 1><<<dim3(16, 48), 256, 0, stream>>>(
        xhi, xlo, wallhi, walllo, qsphi, qsplo, kf, ksphi, ksplo, vf, nullptr);

    // 3. score path: key-split stats + combine + key-split influence
    score1_k<<<1024, 256, 0, stream>>>(qsphi, qsplo, ksphi, ksplo, lp, eep, mxp);
    fixstats_k<<<NH*SEQ/256, 256, 0, stream>>>(lp, eep, mxp, invg, ent, mxa);
    score2_k<<<1024, 256, 0, stream>>>(qsphi, qsplo, ksphi, ksplo, invg, part);
    reduce_infl<<<dim3(SEQ/256, NH), 256, 0, stream>>>(part, red);
    importance_k<<<SEQ/256, 256, 0, stream>>>(ent, mxa, red, imp);
    topk_k<<<SEQ/4, 256, 0, stream>>>(imp, hh);

    // 4. compression weights + cat building (fused k/v variants)
    norms2_k<<<dim3(NH*SEQ/4, 2), 256, 0, stream>>>(kf, vf, wk, wv);
    softw2_k<<<dim3(NH, 2), 256, 0, stream>>>(wk, wv);
    pool2_k<<<dim3(NH*LCOMP*HD/256, 2), 256, 0, stream>>>(kf, vf, wk, wv,
                                                          kchi, kclo, vthi, vtlo);
    padzero_k<<<208, 256, 0, stream>>>(kchi, kclo, vthi, vtlo);
    gather_k<<<NH*NKH*HD/256, 256, 0, stream>>>(kf, vf, hh, kchi, kclo, vthi, vtlo);

    // 5. final attention (LDS-staged flash-style, 64 rows/block, 512 blocks)
    attn_mfma<<<NH * (SEQ/64), 256, 0, stream>>>(qsphi, qsplo, kchi, kclo, vthi, vtlo, aohi, aolo);

    // 6. output projection (BK=64 swizzled staging)
    gemm_lds<64, 64, 0><<<dim3(32, 16), 256, 0, stream>>>(
        aohi, aolo, wohi, wolo, nullptr, nullptr, nullptr, nullptr, nullptr, nullptr, out);
}

// Round 17
// 276.633 us; speedup vs baseline: 1.0927x; 1.0927x over previous
//
#include <hip/hip_runtime.h>
#include <hip/hip_fp16.h>
#include <math.h>

#define SEQ   2048
#define HID   1024
#define NH    16
#define HD    64
#define NKH   204          // heavy hitters = int(2048*0.1)
#define LCOMP 512          // compressed length = 2048/4
#define NCAT  716          // 204 + 512
#define NCATP 768          // padded to multiple of 64 (52 pad keys)
#define SCALE 0.125f       // 1/sqrt(64)

typedef __attribute__((ext_vector_type(8))) short short8;   // 8 bf16 (4 VGPRs)
typedef __attribute__((ext_vector_type(4))) float f32x4;    // MFMA accumulator

// ---- bf16 split helpers (RNE) -------------------------------------------
__device__ __forceinline__ short f2bf(float f) {
    unsigned u = __builtin_bit_cast(unsigned, f);
    u += 0x7FFFu + ((u >> 16) & 1u);
    return (short)(u >> 16);
}
__device__ __forceinline__ float bf2f(short h) {
    unsigned u = ((unsigned)(unsigned short)h) << 16;
    return __builtin_bit_cast(float, u);
}

// async global->LDS, 16B per lane (dwordx4).  LDS dest must be wave-uniform
// base; HW writes base + lane*16.  Global src is per-lane.
__device__ __forceinline__ void gload_lds16(const unsigned short* g, unsigned short* l) {
    __builtin_amdgcn_global_load_lds((const __attribute__((address_space(1))) void*)g,
                                     (__attribute__((address_space(3))) void*)l,
                                     16, 0, 0);
}

// ---------------------------------------------------------------------------
// One-pass splitters: f32 -> bf16 hi/lo.
// ---------------------------------------------------------------------------
__global__ __launch_bounds__(256) void splitx_k(const float* __restrict__ X,
                                                unsigned short* __restrict__ hi,
                                                unsigned short* __restrict__ lo) {
    size_t g = ((size_t)blockIdx.x * 256 + threadIdx.x) * 4;
    float4 v4 = *(const float4*)(X + g);
    ushort4 h4, l4;
    short hb;
    hb = f2bf(v4.x); h4.x = hb; l4.x = (unsigned short)f2bf(v4.x - bf2f(hb));
    hb = f2bf(v4.y); h4.y = hb; l4.y = (unsigned short)f2bf(v4.y - bf2f(hb));
    hb = f2bf(v4.z); h4.z = hb; l4.z = (unsigned short)f2bf(v4.z - bf2f(hb));
    hb = f2bf(v4.w); h4.w = hb; l4.w = (unsigned short)f2bf(v4.w - bf2f(hb));
    *(ushort4*)(hi + g) = h4;
    *(ushort4*)(lo + g) = l4;
}

// All 4 weight splits in one launch; blockIdx.z picks src/dst (wave-uniform).
__global__ __launch_bounds__(256) void splitw4_k(const float* __restrict__ W0,
                                                 const float* __restrict__ W1,
                                                 const float* __restrict__ W2,
                                                 const float* __restrict__ W3,
                                                 unsigned short* __restrict__ h012,
                                                 unsigned short* __restrict__ l012,
                                                 unsigned short* __restrict__ h3,
                                                 unsigned short* __restrict__ l3) {
    __shared__ float tile[64][65];
    int z = blockIdx.z;
    const float* W = (z == 0) ? W0 : (z == 1) ? W1 : (z == 2) ? W2 : W3;
    unsigned short* hi = (z == 3) ? h3 : h012 + (size_t)z * HID * HID;
    unsigned short* lo = (z == 3) ? l3 : l012 + (size_t)z * HID * HID;
    int n0 = blockIdx.x * 64, k0 = blockIdx.y * 64;
    int t = threadIdx.x;
    int r = t >> 4, c4 = (t & 15) * 4;
    #pragma unroll
    for (int i = 0; i < 4; ++i) {
        float4 v4 = *(const float4*)(W + (size_t)(k0 + i*16 + r) * HID + n0 + c4);
        tile[i*16 + r][c4+0] = v4.x; tile[i*16 + r][c4+1] = v4.y;
        tile[i*16 + r][c4+2] = v4.z; tile[i*16 + r][c4+3] = v4.w;
    }
    __syncthreads();
    #pragma unroll
    for (int i = 0; i < 4; ++i) {
        int n = i*16 + r;
        float v0 = tile[c4+0][n], v1 = tile[c4+1][n];
        float v2 = tile[c4+2][n], v3 = tile[c4+3][n];
        ushort4 h4, l4;
        short hb;
        hb = f2bf(v0); h4.x = hb; l4.x = (unsigned short)f2bf(v0 - bf2f(hb));
        hb = f2bf(v1); h4.y = hb; l4.y = (unsigned short)f2bf(v1 - bf2f(hb));
        hb = f2bf(v2); h4.z = hb; l4.z = (unsigned short)f2bf(v2 - bf2f(hb));
        hb = f2bf(v3); h4.w = hb; l4.w = (unsigned short)f2bf(v3 - bf2f(hb));
        size_t o = (size_t)(n0 + n) * HID + k0 + c4;
        *(ushort4*)(hi + o) = h4;
        *(ushort4*)(lo + o) = l4;
    }
}

// ---------------------------------------------------------------------------
// LDS-staged bf16x3 MFMA GEMM.  Block = BM x BN, BK=64, 4 waves,
// wave = (BM/2)m x (BN/2)n.  MODE 1 = fused QKV epilogue, MODE 0 = f32 C.
// r16 structure (kept): XOR chunk-swizzled staging, zero bank conflicts,
// 16 barrier-pairs per block.  Tile curve measured: 128x64 = optimum.
// ---------------------------------------------------------------------------
template<int BM, int BN, int MODE>
__global__ __launch_bounds__(256) void gemm_lds(const unsigned short* __restrict__ Ahi,
                                                const unsigned short* __restrict__ Alo,
                                                const unsigned short* __restrict__ Bthi,
                                                const unsigned short* __restrict__ Btlo,
                                                unsigned short* __restrict__ qhi,
                                                unsigned short* __restrict__ qlo,
                                                float* __restrict__ kf,
                                                unsigned short* __restrict__ khi,
                                                unsigned short* __restrict__ klo,
                                                float* __restrict__ vf,
                                                float* __restrict__ Cf) {
    constexpr int WM = BM / 2, WN = BN / 2;
    constexpr int MT = WM / 16, NT = WN / 16;
    __shared__ __align__(16) unsigned short Ah_s[BM * 64];
    __shared__ __align__(16) unsigned short Al_s[BM * 64];
    __shared__ __align__(16) unsigned short Bh_s[BN * 64];
    __shared__ __align__(16) unsigned short Bl_s[BN * 64];
    int t = threadIdx.x, lane = t & 63, w = t >> 6;
    int quad = lane >> 4, c16 = lane & 15;
    int m0 = blockIdx.x * BM, n0 = blockIdx.y * BN;
    int moff = (w & 1) * WM, noff = (w >> 1) * WN;

    f32x4 acc[MT][NT];
    #pragma unroll
    for (int mt = 0; mt < MT; ++mt)
        #pragma unroll
        for (int nt = 0; nt < NT; ++nt)
            acc[mt][nt] = (f32x4){0.f, 0.f, 0.f, 0.f};

    for (int kt = 0; kt < HID; kt += 64) {
        __syncthreads();
        #pragma unroll
        for (int j = 0; j < BM / 32; ++j) {
            int nb = j * 256 + w * 64;       // wave-uniform LDS chunk base
            int n  = nb + lane;
            int row = n >> 3;                // tile row
            int sc  = ((n & 7) ^ (row & 7)) * 8;   // swizzled source chunk
            gload_lds16(Ahi + (size_t)(m0 + row) * HID + kt + sc, Ah_s + nb*8);
            gload_lds16(Alo + (size_t)(m0 + row) * HID + kt + sc, Al_s + nb*8);
        }
        #pragma unroll
        for (int j = 0; j < BN / 32; ++j) {
            int nb = j * 256 + w * 64;
            int n  = nb + lane;
            int row = n >> 3;
            int sc  = ((n & 7) ^ (row & 7)) * 8;
            gload_lds16(Bthi + (size_t)(n0 + row) * HID + kt + sc, Bh_s + nb*8);
            gload_lds16(Btlo + (size_t)(n0 + row) * HID + kt + sc, Bl_s + nb*8);
        }
        __syncthreads();
        #pragma unroll
        for (int ks = 0; ks < 2; ++ks) {     // two 32-k slices, ascending k
            short8 Bh[NT], Bl[NT];
            #pragma unroll
            for (int nt = 0; nt < NT; ++nt) {
                int row = noff + nt * 16 + c16;
                int s = ((ks*4 + quad) ^ (row & 7)) * 8;
                Bh[nt] = *(const short8*)&Bh_s[row * 64 + s];
                Bl[nt] = *(const short8*)&Bl_s[row * 64 + s];
            }
            #pragma unroll
            for (int mt = 0; mt < MT; ++mt) {
                int row = moff + mt * 16 + c16;
                int s = ((ks*4 + quad) ^ (row & 7)) * 8;
                short8 Ah = *(const short8*)&Ah_s[row * 64 + s];
                short8 Al = *(const short8*)&Al_s[row * 64 + s];
                #pragma unroll
                for (int nt = 0; nt < NT; ++nt) {
                    acc[mt][nt] = __builtin_amdgcn_mfma_f32_16x16x32_bf16(Ah, Bh[nt], acc[mt][nt], 0, 0, 0);
                    acc[mt][nt] = __builtin_amdgcn_mfma_f32_16x16x32_bf16(Al, Bh[nt], acc[mt][nt], 0, 0, 0);
                    acc[mt][nt] = __builtin_amdgcn_mfma_f32_16x16x32_bf16(Ah, Bl[nt], acc[mt][nt], 0, 0, 0);
                }
            }
        }
    }

    #pragma unroll
    for (int mt = 0; mt < MT; ++mt)
    #pragma unroll
    for (int nt = 0; nt < NT; ++nt)
    #pragma unroll
    for (int i = 0; i < 4; ++i) {
        int m  = m0 + moff + mt * 16 + quad * 4 + i;
        int ng = n0 + noff + nt * 16 + c16;
        float val = acc[mt][nt][i];
        if (MODE == 1) {
            int seg = ng >> 10;            // 0=q, 1=k, 2=v
            int nl  = ng & 1023;
            if (seg == 0) {
                size_t o = ((size_t)(nl >> 6) * SEQ + m) * HD + (nl & 63);
                short hb = f2bf(val);
                qhi[o] = (unsigned short)hb;
                qlo[o] = (unsigned short)f2bf(val - bf2f(hb));
            } else if (seg == 1) {
                kf[(size_t)m * HID + nl] = val;
                size_t o = ((size_t)(nl >> 6) * SEQ + m) * HD + (nl & 63);
                short hb = f2bf(val);
                khi[o] = (unsigned short)hb;
                klo[o] = (unsigned short)f2bf(val - bf2f(hb));
            } else {
                vf[(size_t)m * HID + nl] = val;
            }
        } else {
            Cf[(size_t)m * HID + ng] = val;
        }
    }
}

// ---------------------------------------------------------------------------
// Score pipeline (r17): key-split 2-dispatch.  fixstats_k folded away:
// score2 computes inv inline (same f32 add order as fixstats -> bitwise
// identical); importance computes ent/mxa terms inline from lp/eep/mxp
// (same per-h formula and summation order -> bitwise-identical imp).
// ---------------------------------------------------------------------------
__global__ __launch_bounds__(256) void score1_k(const unsigned short* __restrict__ qhi,
                                                const unsigned short* __restrict__ qlo,
                                                const unsigned short* __restrict__ khi,
                                                const unsigned short* __restrict__ klo,
                                                float* __restrict__ lp,
                                                float* __restrict__ eep,
                                                float* __restrict__ mxp) {
    __shared__ __align__(16) unsigned short Kh_s[128 * 64];  // 16 KB
    __shared__ __align__(16) unsigned short Kl_s[128 * 64];  // 16 KB
    int lin = blockIdx.x;
    int swz = (lin & 7) * 128 + (lin >> 3);  // bijective XCD swizzle (1024%8==0)
    int h   = swz >> 6;
    int rem = swz & 63;
    int qb  = rem >> 1;
    int kh2 = rem & 1;                       // key half
    int m0 = qb * 64;
    int kbase = kh2 * 1024;
    int t  = threadIdx.x;
    int lane = t & 63, w = t >> 6;           // w = wave = 16-row group
    int quad = lane >> 4, c16 = lane & 15;

    const unsigned short* qph = qhi + ((size_t)h * SEQ + m0 + w*16 + c16) * HD;
    const unsigned short* qpl = qlo + ((size_t)h * SEQ + m0 + w*16 + c16) * HD;
    short8 Ah0 = *(const short8*)(qph + quad*8);
    short8 Ah1 = *(const short8*)(qph + 32 + quad*8);
    short8 Al0 = *(const short8*)(qpl + quad*8);
    short8 Al1 = *(const short8*)(qpl + 32 + quad*8);

    float l[4] = {}, ee[4] = {};
    float mx[4] = {-1e30f, -1e30f, -1e30f, -1e30f};

    for (int kt = 0; kt < 8; ++kt) {
        int key0 = kbase + kt * 128;
        __syncthreads();
        #pragma unroll
        for (int j = 0; j < 4; ++j) {
            int nb = j*256 + w*64;           // wave-uniform LDS chunk base
            int n  = nb + lane;
            int row = n >> 3;                // key within tile
            int sc  = ((n & 7) ^ (row & 7)) * 8;   // swizzled source chunk
            gload_lds16(khi + ((size_t)h * SEQ + key0 + row) * HD + sc, Kh_s + nb*8);
            gload_lds16(klo + ((size_t)h * SEQ + key0 + row) * HD + sc, Kl_s + nb*8);
        }
        __syncthreads();
        #pragma unroll
        for (int ksub = 0; ksub < 8; ++ksub) {
            int q  = ksub*16 + c16;
            int s0 = (quad       ^ (q & 7)) * 8;
            int s1 = ((quad + 4) ^ (q & 7)) * 8;
            short8 Bh0 = *(const short8*)&Kh_s[q*64 + s0];
            short8 Bh1 = *(const short8*)&Kh_s[q*64 + s1];
            short8 Bl0 = *(const short8*)&Kl_s[q*64 + s0];
            short8 Bl1 = *(const short8*)&Kl_s[q*64 + s1];
            f32x4 acc = {0.f, 0.f, 0.f, 0.f};
            acc = __builtin_amdgcn_mfma_f32_16x16x32_bf16(Ah0, Bh0, acc, 0, 0, 0);
            acc = __builtin_amdgcn_mfma_f32_16x16x32_bf16(Al0, Bh0, acc, 0, 0, 0);
            acc = __builtin_amdgcn_mfma_f32_16x16x32_bf16(Ah0, Bl0, acc, 0, 0, 0);
            acc = __builtin_amdgcn_mfma_f32_16x16x32_bf16(Ah1, Bh1, acc, 0, 0, 0);
            acc = __builtin_amdgcn_mfma_f32_16x16x32_bf16(Al1, Bh1, acc, 0, 0, 0);
            acc = __builtin_amdgcn_mfma_f32_16x16x32_bf16(Ah1, Bl1, acc, 0, 0, 0);
            #pragma unroll
            for (int i = 0; i < 4; ++i) {
                float s = acc[i] * SCALE;
                float e = __expf(s);          // safe: |s| << 88
                l[i]  += e;
                ee[i] += e * s;
                mx[i]  = fmaxf(mx[i], s);
            }
        }
    }

    #pragma unroll
    for (int i = 0; i < 4; ++i) {
        #pragma unroll
        for (int off = 1; off <= 8; off <<= 1) {
            l[i]  += __shfl_xor(l[i], off);
            ee[i] += __shfl_xor(ee[i], off);
            mx[i]  = fmaxf(mx[i], __shfl_xor(mx[i], off));
        }
    }
    if (c16 == 0) {
        #pragma unroll
        for (int i = 0; i < 4; ++i) {
            size_t o = ((size_t)kh2 * NH + h) * SEQ + m0 + w*16 + quad*4 + i;
            lp[o]  = l[i];
            eep[o] = ee[i];
            mxp[o] = mx[i];
        }
    }
}

__global__ __launch_bounds__(256) void score2_k(const unsigned short* __restrict__ qhi,
                                                const unsigned short* __restrict__ qlo,
                                                const unsigned short* __restrict__ khi,
                                                const unsigned short* __restrict__ klo,
                                                const float* __restrict__ lp,
                                                __half* __restrict__ part) {
    __shared__ __align__(16) unsigned short Kh_s[128 * 64];  // 16 KB
    __shared__ __align__(16) unsigned short Kl_s[128 * 64];  // 16 KB
    int lin = blockIdx.x;
    int swz = (lin & 7) * 128 + (lin >> 3);  // bijective XCD swizzle
    int h   = swz >> 6;
    int rem = swz & 63;
    int qb  = rem >> 1;
    int kh2 = rem & 1;
    int m0 = qb * 64;
    int kbase = kh2 * 1024;
    int t  = threadIdx.x;
    int lane = t & 63, w = t >> 6;
    int quad = lane >> 4, c16 = lane & 15;

    const unsigned short* qph = qhi + ((size_t)h * SEQ + m0 + w*16 + c16) * HD;
    const unsigned short* qpl = qlo + ((size_t)h * SEQ + m0 + w*16 + c16) * HD;
    short8 Ah0 = *(const short8*)(qph + quad*8);
    short8 Ah1 = *(const short8*)(qph + 32 + quad*8);
    short8 Al0 = *(const short8*)(qpl + quad*8);
    short8 Al1 = *(const short8*)(qpl + 32 + quad*8);

    float invv[4];
    #pragma unroll
    for (int i = 0; i < 4; ++i) {
        size_t o = (size_t)h * SEQ + m0 + w*16 + quad*4 + i;
        invv[i] = 1.f / (lp[o] + lp[(size_t)NH*SEQ + o]);   // == fixstats iv
    }

    __half* pslab = part + ((size_t)(h * 32 + qb) * 4 + w) * SEQ;
    for (int kt = 0; kt < 8; ++kt) {
        int key0 = kbase + kt * 128;
        __syncthreads();
        #pragma unroll
        for (int j = 0; j < 4; ++j) {
            int nb = j*256 + w*64;
            int n  = nb + lane;
            int row = n >> 3;
            int sc  = ((n & 7) ^ (row & 7)) * 8;
            gload_lds16(khi + ((size_t)h * SEQ + key0 + row) * HD + sc, Kh_s + nb*8);
            gload_lds16(klo + ((size_t)h * SEQ + key0 + row) * HD + sc, Kl_s + nb*8);
        }
        __syncthreads();
        #pragma unroll
        for (int ksub = 0; ksub < 8; ++ksub) {
            int q  = ksub*16 + c16;
            int s0 = (quad       ^ (q & 7)) * 8;
            int s1 = ((quad + 4) ^ (q & 7)) * 8;
            short8 Bh0 = *(const short8*)&Kh_s[q*64 + s0];
            short8 Bh1 = *(const short8*)&Kh_s[q*64 + s1];
            short8 Bl0 = *(const short8*)&Kl_s[q*64 + s0];
            short8 Bl1 = *(const short8*)&Kl_s[q*64 + s1];
            f32x4 acc = {0.f, 0.f, 0.f, 0.f};
            acc = __builtin_amdgcn_mfma_f32_16x16x32_bf16(Ah0, Bh0, acc, 0, 0, 0);
            acc = __builtin_amdgcn_mfma_f32_16x16x32_bf16(Al0, Bh0, acc, 0, 0, 0);
            acc = __builtin_amdgcn_mfma_f32_16x16x32_bf16(Ah0, Bl0, acc, 0, 0, 0);
            acc = __builtin_amdgcn_mfma_f32_16x16x32_bf16(Ah1, Bh1, acc, 0, 0, 0);
            acc = __builtin_amdgcn_mfma_f32_16x16x32_bf16(Al1, Bh1, acc, 0, 0, 0);
            acc = __builtin_amdgcn_mfma_f32_16x16x32_bf16(Ah1, Bl1, acc, 0, 0, 0);
            float cs = 0.f;
            #pragma unroll
            for (int i = 0; i < 4; ++i)
                cs += __expf(acc[i] * SCALE) * invv[i];
            cs += __shfl_xor(cs, 16);
            cs += __shfl_xor(cs, 32);    // sum over the 4 quads (16 rows)
            if (quad == 0)
                pslab[key0 + ksub*16 + c16] = __float2half(cs);
        }
    }
}

// stage-1 influence reduction: red[h][s] = sum of head h's 128 wave-slabs
__global__ __launch_bounds__(256) void reduce_infl(const __half* __restrict__ part,
                                                   float* __restrict__ red) {
    int s = blockIdx.x * 256 + threadIdx.x;
    int g = blockIdx.y;
    const __half* p = part + (size_t)g * 128 * SEQ + s;
    float a = 0.f;
    #pragma unroll 16
    for (int i = 0; i < 128; ++i) a += __half2float(p[(size_t)i * SEQ]);
    red[(size_t)g * SEQ + s] = a;
}

// importance: ent/mxa terms computed inline from the key-half partials
// (identical per-h formula and h-summation order as the old fixstats ->
// importance pair; bitwise-identical imp).
__global__ __launch_bounds__(256) void importance_k(const float* __restrict__ lp,
                                                    const float* __restrict__ eep,
                                                    const float* __restrict__ mxp,
                                                    const float* __restrict__ red,
                                                    float* __restrict__ imp) {
    int s = blockIdx.x * 256 + threadIdx.x;
    float es = 0.f, ms = 0.f;
    #pragma unroll
    for (int h = 0; h < NH; ++h) {
        size_t idx = (size_t)h * SEQ + s;
        float lf  = lp[idx]  + lp[(size_t)NH*SEQ + idx];
        float eef = eep[idx] + eep[(size_t)NH*SEQ + idx];
        float mf  = fmaxf(mxp[idx], mxp[(size_t)NH*SEQ + idx]);
        float iv  = 1.f / lf;
        es += __logf(lf) - eef * iv;
        ms += __expf(mf) * iv;
    }
    float inf = 0.f;
    #pragma unroll
    for (int g = 0; g < NH; ++g) inf += red[(size_t)g * SEQ + s];
    imp[s] = (-0.4f*es + 0.3f*ms + 0.3f*inf) * (1.f/16.f);
}

// Deterministic top-k by rank counting — wave-parallel (r13, kept: 76 -> ~3 us).
__global__ __launch_bounds__(256) void topk_k(const float* __restrict__ imp,
                                              int* __restrict__ hh) {
    __shared__ float si[SEQ];
    int t = threadIdx.x;
    for (int i = t; i < SEQ; i += 256) si[i] = imp[i];
    __syncthreads();
    int lane = t & 63, w = t >> 6;
    int s = blockIdx.x * 4 + w;
    float v = si[s];
    int rank = 0;
    #pragma unroll
    for (int j = 0; j < SEQ / 64; ++j) {
        int i = j * 64 + lane;
        float u = si[i];
        rank += (u > v) || (u == v && i < s);
    }
    #pragma unroll
    for (int off = 32; off; off >>= 1) rank += __shfl_xor(rank, off);
    if (lane == 0 && rank < NKH) hh[rank] = s;
}

// per-(h,s) L2 norms for BOTH k and v (blockIdx.y selects tensor)
__global__ __launch_bounds__(256) void norms2_k(const float* __restrict__ kf,
                                                const float* __restrict__ vf,
                                                float* __restrict__ wk,
                                                float* __restrict__ wv) {
    int sel = blockIdx.y;
    const float* x = sel ? vf : kf;
    float* n = sel ? wv : wk;
    int t = threadIdx.x;
    int wid = blockIdx.x * 4 + (t >> 6);
    int lane = t & 63;
    int h = wid >> 11, s = wid & 2047;
    float v = x[(size_t)s * HID + h * HD + lane];
    float ss = v * v;
    #pragma unroll
    for (int off = 32; off; off >>= 1) ss += __shfl_xor(ss, off);
    if (lane == 0) n[h*SEQ + s] = sqrtf(ss);
}

// in-place softmax over SEQ per head for BOTH wk and wv
__global__ __launch_bounds__(256) void softw2_k(float* __restrict__ wk,
                                                float* __restrict__ wv) {
    __shared__ float red[8];
    int h = blockIdx.x, t = threadIdx.x, lane = t & 63, w = t >> 6;
    float* nh = (blockIdx.y ? wv : wk) + (size_t)h * SEQ;
    float m = -1e30f;
    for (int i = t; i < SEQ; i += 256) m = fmaxf(m, nh[i]);
    #pragma unroll
    for (int off = 32; off; off >>= 1) m = fmaxf(m, __shfl_xor(m, off));
    if (lane == 0) red[w] = m;
    __syncthreads();
    m = fmaxf(fmaxf(red[0], red[1]), fmaxf(red[2], red[3]));
    float z = 0.f;
    for (int i = t; i < SEQ; i += 256) z += __expf(nh[i] - m);
    #pragma unroll
    for (int off = 32; off; off >>= 1) z += __shfl_xor(z, off);
    if (lane == 0) red[4 + w] = z;
    __syncthreads();
    z = red[4] + red[5] + red[6] + red[7];
    for (int i = t; i < SEQ; i += 256) nh[i] = __expf(nh[i] - m) / z;
}

// ---------------------------------------------------------------------------
// Merged cat builder (r17): pool (y=0 K, y=1 V) + gather/padzero (y=2).
// Bodies identical to the former pool2_k / gather_k / padzero_k.
// ---------------------------------------------------------------------------
__global__ __launch_bounds__(256) void buildcat_k(const float* __restrict__ kf,
                                                  const float* __restrict__ vf,
                                                  const float* __restrict__ wk,
                                                  const float* __restrict__ wv,
                                                  const int* __restrict__ hh,
                                                  unsigned short* __restrict__ khi,
                                                  unsigned short* __restrict__ klo,
                                                  unsigned short* __restrict__ vthi,
                                                  unsigned short* __restrict__ vtlo) {
    int y = blockIdx.y;
    if (y < 2) {
        // ---- pooling path (former pool2_k), sel = y ----
        int sel = y;
        const float* src = sel ? vf : kf;
        const float* w   = sel ? wv : wk;
        int g = blockIdx.x * 256 + threadIdx.x;
        int d = g & 63, rest = g >> 6;
        int l = rest & 511, h = rest >> 9;
        const float* wp = w + (size_t)h * SEQ + l * 4;
        float w0 = wp[0], w1 = wp[1], w2 = wp[2], w3 = wp[3];
        float wsum = w0 + w1 + w2 + w3 + 1e-8f;
        size_t base = (size_t)(l*4) * HID + h * HD + d;
        float val = (src[base]*w0 + src[base+HID]*w1 + src[base+2*HID]*w2 + src[base+3*HID]*w3) / wsum;
        short hb = f2bf(val);
        if (sel) {
            size_t dst = ((size_t)h * HD + d) * NCATP + NKH + l;
            vthi[dst] = (unsigned short)hb;
            vtlo[dst] = (unsigned short)f2bf(val - bf2f(hb));
        } else {
            size_t dst = ((size_t)h * NCATP + NKH + l) * HD + d;
            khi[dst] = (unsigned short)hb;
            klo[dst] = (unsigned short)f2bf(val - bf2f(hb));
        }
    } else {
        int b = blockIdx.x;
        if (b < NH * NKH * HD / 256) {
            // ---- gather path (former gather_k) ----
            int g = b * 256 + threadIdx.x;
            int d = g & 63, rest = g >> 6;
            int i = rest % NKH, h = rest / NKH;
            int s = hh[i];
            float kv = kf[(size_t)s * HID + h * HD + d];
            float vv = vf[(size_t)s * HID + h * HD + d];
            size_t kd = ((size_t)h * NCATP + i) * HD + d;
            size_t vd = ((size_t)h * HD + d) * NCATP + i;
            short hb = f2bf(kv);
            khi[kd] = (unsigned short)hb;
            klo[kd] = (unsigned short)f2bf(kv - bf2f(hb));
            hb = f2bf(vv);
            vthi[vd] = (unsigned short)hb;
            vtlo[vd] = (unsigned short)f2bf(vv - bf2f(hb));
        } else {
            // ---- padzero path (former padzero_k) ----
            int b2 = b - NH * NKH * HD / 256;
            int g = b2 * 256 + threadIdx.x;
            if (b2 >= 208 || g >= NH * (NCATP - NCAT) * HD) return;
            int d = g & 63, rest = g >> 6;
            int i = rest % (NCATP - NCAT), h = rest / (NCATP - NCAT);
            size_t kd = ((size_t)h * NCATP + NCAT + i) * HD + d;
            size_t vd = ((size_t)h * HD + d) * NCATP + NCAT + i;
            khi[kd] = 0; klo[kd] = 0;
            vthi[vd] = 0; vtlo[vd] = 0;
        }
    }
}

// ---------------------------------------------------------------------------
// Final attention — LDS-staged flash-style (r6, kept: 101.6 -> ~30 us).
// ---------------------------------------------------------------------------
__global__ __launch_bounds__(256) void attn_mfma(const unsigned short* __restrict__ qhi,
                                                 const unsigned short* __restrict__ qlo,
                                                 const unsigned short* __restrict__ kchi,
                                                 const unsigned short* __restrict__ kclo,
                                                 const unsigned short* __restrict__ vthi,
                                                 const unsigned short* __restrict__ vtlo,
                                                 unsigned short* __restrict__ aohi,
                                                 unsigned short* __restrict__ aolo) {
    __shared__ __align__(16) unsigned short Kh_s[64 * 64];   // [key][d-chunk swz]
    __shared__ __align__(16) unsigned short Kl_s[64 * 64];
    __shared__ __align__(16) unsigned short Vh_s[64 * 64];   // [dim][k-chunk swz]
    __shared__ __align__(16) unsigned short Vl_s[64 * 64];
    __shared__ __align__(16) unsigned short Ph_s[4][16][72]; // [wave][row][key]
    __shared__ __align__(16) unsigned short Pl_s[4][16][72];

    int lin = blockIdx.x;
    int swz = (lin & 7) * 64 + (lin >> 3);   // bijective XCD swizzle (512%8==0)
    int h  = swz >> 5;
    int m0 = (swz & 31) * 64;
    int t  = threadIdx.x;
    int lane = t & 63, w = t >> 6;           // w = wave = 16-row group
    int quad = lane >> 4, c16 = lane & 15;

    // Q fragments for this wave's 16 rows
    const unsigned short* qph = qhi + ((size_t)h * SEQ + m0 + w*16 + c16) * HD;
    const unsigned short* qpl = qlo + ((size_t)h * SEQ + m0 + w*16 + c16) * HD;
    short8 Ah0 = *(const short8*)(qph + quad*8);
    short8 Ah1 = *(const short8*)(qph + 32 + quad*8);
    short8 Al0 = *(const short8*)(qpl + quad*8);
    short8 Al1 = *(const short8*)(qpl + 32 + quad*8);

    f32x4 ohh[4], olh[4], ohl[4];
    #pragma unroll
    for (int dt = 0; dt < 4; ++dt) {
        ohh[dt] = (f32x4){0.f,0.f,0.f,0.f};
        olh[dt] = (f32x4){0.f,0.f,0.f,0.f};
        ohl[dt] = (f32x4){0.f,0.f,0.f,0.f};
    }
    float l[4] = {};

    for (int kt = 0; kt < 12; ++kt) {
        int key0 = kt * 64;
        __syncthreads();                 // prev tile's LDS readers done
        #pragma unroll
        for (int j = 0; j < 2; ++j) {
            int nb = j*256 + (t & 192);  // wave-uniform LDS chunk base
            int n  = nb + lane;
            int row = n >> 3;            // key (K) / dim (V)
            int sc  = ((n & 7) ^ (row & 7)) * 8;   // swizzled source chunk (shorts)
            gload_lds16(kchi + ((size_t)h * NCATP + key0 + row) * HD + sc, Kh_s + nb*8);
            gload_lds16(kclo + ((size_t)h * NCATP + key0 + row) * HD + sc, Kl_s + nb*8);
            gload_lds16(vthi + ((size_t)h * HD + row) * NCATP + key0 + sc, Vh_s + nb*8);
            gload_lds16(vtlo + ((size_t)h * HD + row) * NCATP + key0 + sc, Vl_s + nb*8);
        }
        __syncthreads();                 // drain: tiles ready

        // ---- QK: 4 sub-tiles of 16 keys ----
        #pragma unroll
        for (int ksub = 0; ksub < 4; ++ksub) {
            int q  = ksub*16 + c16;      // key row in LDS (lane's B column)
            int s0 = (quad       ^ (q & 7)) * 8;
            int s1 = ((quad + 4) ^ (q & 7)) * 8;
            short8 Bh0 = *(const short8*)&Kh_s[q*64 + s0];
            short8 Bh1 = *(const short8*)&Kh_s[q*64 + s1];
            short8 Bl0 = *(const short8*)&Kl_s[q*64 + s0];
            short8 Bl1 = *(const short8*)&Kl_s[q*64 + s1];
            f32x4 acc = {0.f, 0.f, 0.f, 0.f};
            acc = __builtin_amdgcn_mfma_f32_16x16x32_bf16(Ah0, Bh0, acc, 0, 0, 0);
            acc = __builtin_amdgcn_mfma_f32_16x16x32_bf16(Al0, Bh0, acc, 0, 0, 0);
            acc = __builtin_amdgcn_mfma_f32_16x16x32_bf16(Ah0, Bl0, acc, 0, 0, 0);
            acc = __builtin_amdgcn_mfma_f32_16x16x32_bf16(Ah1, Bh1, acc, 0, 0, 0);
            acc = __builtin_amdgcn_mfma_f32_16x16x32_bf16(Al1, Bh1, acc, 0, 0, 0);
            acc = __builtin_amdgcn_mfma_f32_16x16x32_bf16(Ah1, Bl1, acc, 0, 0, 0);
            bool ok = (key0 + q) < NCAT;
            #pragma unroll
            for (int i = 0; i < 4; ++i) {
                float e = ok ? __expf(acc[i] * SCALE) : 0.f;
                l[i] += e;
                short eh = f2bf(e);
                Ph_s[w][quad*4 + i][ksub*16 + c16] = (unsigned short)eh;
                Pl_s[w][quad*4 + i][ksub*16 + c16] = (unsigned short)f2bf(e - bf2f(eh));
            }
        }

        // ---- PV: 4 dim-tiles x 2 k-steps (same-wave P dep; compiler waits) ----
        #pragma unroll
        for (int dt = 0; dt < 4; ++dt) {
            int dl = dt*16 + c16;        // dim row in LDS (lane's B column)
            #pragma unroll
            for (int ks = 0; ks < 2; ++ks) {
                short8 Ph = *(const short8*)&Ph_s[w][c16][ks*32 + quad*8];
                short8 Pl = *(const short8*)&Pl_s[w][c16][ks*32 + quad*8];
                int sv = ((ks*4 + quad) ^ (dl & 7)) * 8;
                short8 Vh = *(const short8*)&Vh_s[dl*64 + sv];
                short8 Vl = *(const short8*)&Vl_s[dl*64 + sv];
                ohh[dt] = __builtin_amdgcn_mfma_f32_16x16x32_bf16(Ph, Vh, ohh[dt], 0, 0, 0);
                olh[dt] = __builtin_amdgcn_mfma_f32_16x16x32_bf16(Pl, Vh, olh[dt], 0, 0, 0);
                ohl[dt] = __builtin_amdgcn_mfma_f32_16x16x32_bf16(Ph, Vl, ohl[dt], 0, 0, 0);
            }
        }
    }

    // ---- epilogue: l reduce over the 16-lane key group, normalize, write ----
    #pragma unroll
    for (int i = 0; i < 4; ++i) {
        #pragma unroll
        for (int off = 1; off <= 8; off <<= 1) l[i] += __shfl_xor(l[i], off);
    }
    float inv[4];
    #pragma unroll
    for (int i = 0; i < 4; ++i) inv[i] = 1.f / l[i];

    #pragma unroll
    for (int dt = 0; dt < 4; ++dt)
    #pragma unroll
    for (int i = 0; i < 4; ++i) {
        float val = (ohh[dt][i] + olh[dt][i] + ohl[dt][i]) * inv[i];
        int row = m0 + w*16 + quad*4 + i;
        int dim = dt*16 + c16;
        size_t o = (size_t)row * HID + h * HD + dim;
        short hb = f2bf(val);
        aohi[o] = (unsigned short)hb;
        aolo[o] = (unsigned short)f2bf(val - bf2f(hb));
    }
}

// ---------------------------------------------------------------------------
extern "C" void kernel_launch(void* const* d_in, const int* in_sizes, int n_in,
                              void* d_out, int out_size, void* d_ws, size_t ws_size,
                              hipStream_t stream) {
    const float* x  = (const float*)d_in[0];
    const float* Wq = (const float*)d_in[1];
    const float* Wk = (const float*)d_in[2];
    const float* Wv = (const float*)d_in[3];
    const float* Wo = (const float*)d_in[4];
    float* out = (float*)d_out;

    char* base = (char*)d_ws;                       // 58 MB total
    const size_t MB = 1u << 20;
    float* kf = (float*)(base + 0);                 // 8 MB
    float* vf = (float*)(base + 8*MB);              // 8 MB
    unsigned short* xhi = (unsigned short*)(base + 16*MB);   // 4 MB
    unsigned short* xlo = (unsigned short*)(base + 20*MB);   // 4 MB
    unsigned short* wallhi = (unsigned short*)(base + 24*MB); // 6 MB [Wq|Wk|Wv]
    unsigned short* walllo = (unsigned short*)(base + 30*MB); // 6 MB
    unsigned short* wohi = (unsigned short*)(base + 36*MB);  // 2 MB
    unsigned short* wolo = (unsigned short*)(base + 38*MB);  // 2 MB
    unsigned short* qsphi = (unsigned short*)(base + 40*MB); // 4 MB [h][s][d]
    unsigned short* qsplo = (unsigned short*)(base + 44*MB);
    unsigned short* ksphi = (unsigned short*)(base + 48*MB); // 4 MB [h][s][d]
    unsigned short* ksplo = (unsigned short*)(base + 52*MB);
    // aliases (ordered reuse on the in-order stream):
    unsigned short* aohi = xhi;                     // x dead after gemm_qkv
    unsigned short* aolo = xlo;
    __half* part = (__half*)(base + 16*MB);         // 8 MB (xhi+xlo region):
                                                    // written after gemm_qkv,
                                                    // consumed by reduce_infl
                                                    // before attn_mfma writes ao
    const size_t CATB = (size_t)NH * NCATP * HD * 2; // 1.5 MB
    unsigned short* kchi = (unsigned short*)(base + 48*MB);  // after score path
    unsigned short* kclo = (unsigned short*)(base + 48*MB + CATB);
    unsigned short* vthi = (unsigned short*)(base + 48*MB + 2*CATB);
    unsigned short* vtlo = (unsigned short*)(base + 48*MB + 3*CATB);
    // small buffers
    char* sm = base + 56*MB;
    float* imp  = (float*)sm;                 sm += SEQ*4;
    int*   hh   = (int*)sm;                   sm += 256*4;
    float* wk   = (float*)sm;                 sm += NH*SEQ*4;
    float* wv   = (float*)sm;                 sm += NH*SEQ*4;
    float* red  = (float*)sm;                 sm += NH*SEQ*4;   // 128 KB
    float* lp   = (float*)sm;                 sm += 2*NH*SEQ*4; // 256 KB
    float* eep  = (float*)sm;                 sm += 2*NH*SEQ*4; // 256 KB
    float* mxp  = (float*)sm;                 // 256 KB (total ~1.15 MB < 2 MB)

    // 1. split inputs (one launch for all 4 weights)
    splitx_k<<<SEQ*HID/1024, 256, 0, stream>>>(x, xhi, xlo);
    splitw4_k<<<dim3(16,16,4), 256, 0, stream>>>(Wq, Wk, Wv, Wo,
                                                 wallhi, walllo, wohi, wolo);

    // 2. fused QKV projection (128x64 tile, BK=64 swizzled, 0 conflicts)
    gemm_lds<128, 64, 1><<<dim3(16, 48), 256, 0, stream>>>(
        xhi, xlo, wallhi, walllo, qsphi, qsplo, kf, ksphi, ksplo, vf, nullptr);

    // 3. score path: key-split stats + key-split influence (inv inline)
    score1_k<<<1024, 256, 0, stream>>>(qsphi, qsplo, ksphi, ksplo, lp, eep, mxp);
    score2_k<<<1024, 256, 0, stream>>>(qsphi, qsplo, ksphi, ksplo, lp, part);
    reduce_infl<<<dim3(SEQ/256, NH), 256, 0, stream>>>(part, red);
    importance_k<<<SEQ/256, 256, 0, stream>>>(lp, eep, mxp, red, imp);
    topk_k<<<SEQ/4, 256, 0, stream>>>(imp, hh);

    // 4. compression weights + merged cat builder
    norms2_k<<<dim3(NH*SEQ/4, 2), 256, 0, stream>>>(kf, vf, wk, wv);
    softw2_k<<<dim3(NH, 2), 256, 0, stream>>>(wk, wv);
    buildcat_k<<<dim3(NH*LCOMP*HD/256, 3), 256, 0, stream>>>(
        kf, vf, wk, wv, hh, kchi, kclo, vthi, vtlo);

    // 5. final attention (LDS-staged flash-style, 64 rows/block, 512 blocks)
    attn_mfma<<<NH * (SEQ/64), 256, 0, stream>>>(qsphi, qsplo, kchi, kclo, vthi, vtlo, aohi, aolo);

    // 6. output projection (BK=64 swizzled staging)
    gemm_lds<64, 64, 0><<<dim3(32, 16), 256, 0, stream>>>(
        aohi, aolo, wohi, wolo, nullptr, nullptr, nullptr, nullptr, nullptr, nullptr, out);
}